// Round 14
// baseline (141.786 us; speedup 1.0000x reference)
//
#include <hip/hip_runtime.h>
#include <math.h>
#include <type_traits>

// ---------------------------------------------------------------------------
// CapsNet forward, fused routing, Gram-trick + 2-sample W amortization.
//   iters 0,1 per (b,o):  y=Hc;  n2=yGy+2sc(y.gb)+sc^2 bb2;  u=scale(Gy+sc gb)
//   iter 2 streams WT for v.  Blocks: 256 = 4 o-quarters x 64 sample-pairs.
// Round-14:
//   * dual h layout back (round-6 lesson): HT[s][i][c] for the Y phase
//     (conflict-free b32 column reads) + HC[s][c][i] for DB.  Kills the
//     8-way Y-phase bank conflict introduced in round 10 (4.39M cycles).
//   * prep: conv split by hw-halves into 256 blocks (squash block-local),
//     W-prep/den0 dispatched first; 379 blocks co-resident in one wave.
// ---------------------------------------------------------------------------

#define SYS_ST(p, v) __hip_atomic_store((p), (v), __ATOMIC_RELAXED, __HIP_MEMORY_SCOPE_SYSTEM)
#define SYS_LD(p)    __hip_atomic_load((p), __ATOMIC_RELAXED, __HIP_MEMORY_SCOPE_SYSTEM)

typedef float v4f __attribute__((ext_vector_type(4)));

__device__ __forceinline__ void sys_st4(float* p, float4 q) {
    v4f v; v[0] = q.x; v[1] = q.y; v[2] = q.z; v[3] = q.w;
    asm volatile("global_store_dwordx4 %0, %1, off sc0 sc1" :: "v"(p), "v"(v) : "memory");
}

// blocks 0-63: W1 o-prep | 64-73: W2 o-prep | 74-121: den0 | 122: flags |
// 123-378: conv+squash (sample b = id>>1, hw-half hh = id&1)
__global__ __launch_bounds__(512) void prep_kernel(
    const float* __restrict__ x, const float* __restrict__ Wb,
    const float* __restrict__ bb,
    const float* __restrict__ W1, const float* __restrict__ b1,
    const float* __restrict__ W2, const float* __restrict__ b2,
    const float* __restrict__ b_basic,
    float* __restrict__ h,
    float* __restrict__ WT1, float* __restrict__ G1,
    float* __restrict__ gb1, float* __restrict__ bb21,
    float* __restrict__ WT2, float* __restrict__ G2,
    float* __restrict__ gb2, float* __restrict__ bb22,
    float* __restrict__ den0, int* __restrict__ flags)
{
    __shared__ float smem[8480];
    const int blk = blockIdx.x;
    const int t = threadIdx.x;

    if (blk < 74) {
        // ------------- per-o W prep (proven 256-thread code, t<256) -------
        const bool w1 = blk < 64;
        const int o = w1 ? blk : (blk - 64);
        const float* W    = w1 ? W1 : W2;
        const float* bias = w1 ? b1 : b2;
        float* WT  = w1 ? WT1  : WT2;
        float* G   = w1 ? G1   : G2;
        float* gb  = w1 ? gb1  : gb2;
        float* bb2 = w1 ? bb21 : bb22;
        float* WS = smem;                 // [64][68] = W_o as [d][c]
        if (t < 256) {
            #pragma unroll
            for (int p = 0; p < 4; ++p) {
                int idx = t + p * 256;
                int d = idx >> 4, c0 = (idx & 15) * 4;
                *(float4*)&WS[d * 68 + c0] =
                    *(const float4*)&W[((size_t)o * 64 + d) * 64 + c0];
            }
        }
        __syncthreads();
        if (t < 256) {
            {   // transpose WT[o][c][d]
                const int Q = t & 15, R = t >> 4;
                #pragma unroll
                for (int p = 0; p < 4; ++p) {
                    int c = R + 16 * p;
                    float4 v;
                    v.x = WS[(4 * Q + 0) * 68 + c];
                    v.y = WS[(4 * Q + 1) * 68 + c];
                    v.z = WS[(4 * Q + 2) * 68 + c];
                    v.w = WS[(4 * Q + 3) * 68 + c];
                    *(float4*)&WT[((size_t)o * 64 + c) * 64 + 4 * Q] = v;
                }
            }
            {   // Gram
                const int c1 = t >> 2, j = t & 3;
                float acc[16];
                #pragma unroll
                for (int g = 0; g < 16; ++g) acc[g] = 0.f;
                for (int d = 0; d < 64; ++d) {
                    float a = WS[d * 68 + c1];
                    #pragma unroll
                    for (int g = 0; g < 16; ++g)
                        acc[g] = fmaf(a, WS[d * 68 + j * 16 + g], acc[g]);
                }
                #pragma unroll
                for (int g = 0; g < 16; ++g)
                    G[(size_t)o * 4096 + c1 * 64 + j * 16 + g] = acc[g];
            }
            if (t < 64) {
                float s = 0.f;
                for (int d = 0; d < 64; ++d) s = fmaf(bias[o * 64 + d], WS[d * 68 + t], s);
                gb[o * 64 + t] = s;
            }
            if (t == 0) {
                float s = 0.f;
                for (int d = 0; d < 64; ++d) { float bv = bias[o * 64 + d]; s = fmaf(bv, bv, s); }
                bb2[o] = s;
            }
        }
    } else if (blk < 122) {
        const int g = (blk - 74) * 512 + t;        // 24576 total
        const int L = g >> 13, b = (g >> 6) & 127, i = g & 63;
        const float* bp = b_basic + (((size_t)L * 128 + b) << 12) + i;
        float s = 0.f;
        for (int o = 0; o < 64; ++o) s += expf(bp[o * 64]);
        den0[((size_t)L * 128 + b) * 64 + i] = s;
    } else if (blk == 122) {
        for (int i = t; i < 4096; i += 512) flags[i] = 0;
    } else {
        // -------- conv3x3+bias+ReLU+channel-squash, hw-half per block -----
        float* xs  = smem;            // [64][100] padded
        float* hs  = smem + 6400;     // [64][32]  (this half's hw)
        float* scl = smem + 8448;     // [32]
        const int id = blk - 123;
        const int b = id >> 1, hh = id & 1;
        for (int idx = t; idx < 6400; idx += 512) xs[idx] = 0.f;
        __syncthreads();
        #pragma unroll
        for (int k2 = 0; k2 < 2; ++k2) {
            int idx4 = t + k2 * 512;
            float4 v = *(const float4*)&x[(size_t)b * 4096 + idx4 * 4];
            int e0 = idx4 * 4;
            int c  = e0 >> 6;
            int hw = e0 & 63;
            int r = hw >> 3, cc = hw & 7;
            float* xp = &xs[c * 100 + (r + 1) * 10 + (cc + 1)];
            xp[0] = v.x; xp[1] = v.y; xp[2] = v.z; xp[3] = v.w;
        }
        __syncthreads();
        const int oc = t >> 3;        // 0..63, 8 threads per oc
        const int hg = t & 7;         // 4 hw each within the half
        float acc[4] = {0.f, 0.f, 0.f, 0.f};
        const float* wp = Wb + (size_t)oc * 576;
        for (int ic = 0; ic < 64; ++ic) {
            float w[9];
            #pragma unroll
            for (int j = 0; j < 9; ++j) w[j] = wp[ic * 9 + j];
            const float* xr = &xs[ic * 100];
            #pragma unroll
            for (int k = 0; k < 4; ++k) {
                int hw = hh * 32 + hg * 4 + k;
                int r = hw >> 3, cc = hw & 7;
                int p0 = r * 10 + cc;
                float a = acc[k];
                a = fmaf(w[0], xr[p0],      a);
                a = fmaf(w[1], xr[p0 + 1],  a);
                a = fmaf(w[2], xr[p0 + 2],  a);
                a = fmaf(w[3], xr[p0 + 10], a);
                a = fmaf(w[4], xr[p0 + 11], a);
                a = fmaf(w[5], xr[p0 + 12], a);
                a = fmaf(w[6], xr[p0 + 20], a);
                a = fmaf(w[7], xr[p0 + 21], a);
                a = fmaf(w[8], xr[p0 + 22], a);
                acc[k] = a;
            }
        }
        float bias = bb[oc];
        #pragma unroll
        for (int k = 0; k < 4; ++k) {
            float v = acc[k] + bias;
            hs[oc * 32 + hg * 4 + k] = v > 0.f ? v : 0.f;
        }
        __syncthreads();
        if (t < 32) {
            float n2 = 0.f;
            for (int c = 0; c < 64; ++c) { float v = hs[c * 32 + t]; n2 = fmaf(v, v, n2); }
            scl[t] = (n2 / (1.f + n2)) * rsqrtf(n2 + 1e-8f);
        }
        __syncthreads();
        {
            float4 o;
            o.x = hs[oc * 32 + hg * 4 + 0] * scl[hg * 4 + 0];
            o.y = hs[oc * 32 + hg * 4 + 1] * scl[hg * 4 + 1];
            o.z = hs[oc * 32 + hg * 4 + 2] * scl[hg * 4 + 2];
            o.w = hs[oc * 32 + hg * 4 + 3] * scl[hg * 4 + 3];
            *(float4*)&h[(size_t)b * 4096 + oc * 64 + hh * 32 + hg * 4] = o;
        }
    }
}

__global__ __launch_bounds__(1024, 4) void caps_fused(
    const float* __restrict__ h0,
    const float* __restrict__ WT1, const float* __restrict__ G1,
    const float* __restrict__ gb1, const float* __restrict__ bb21,
    const float* __restrict__ b1,
    const float* __restrict__ WT2, const float* __restrict__ G2,
    const float* __restrict__ gb2, const float* __restrict__ bb22,
    const float* __restrict__ b2,
    const float* __restrict__ b_basic, const float* __restrict__ b_cls,
    const float* __restrict__ den0,
    float* __restrict__ xbuf,   // [2][256][128]  den partial ping-pong
    float* __restrict__ vbuf,   // [256][2048]    layer-end v chunks
    int*   __restrict__ flags,  // [256*16]
    float* __restrict__ out)
{
    __shared__ float HC[8704];    // [2][64][68]  h as [c][i]  (DB phase)
    __shared__ float HT[8192];    // [2][64][64]  h as [i][c]  (Y phase, b32)
    __shared__ float CC[2048];    // [32 rows][64] per-(o,s) comm rows
    __shared__ float PP[2048];    // [2][16][64] softmax partials
                                  // total 83968 B -> 1 block/CU

    const int B    = blockIdx.x;      // 0..255
    const int q    = B >> 6;          // o-quarter 0..3
    const int p    = B & 63;          // sample-pair; samples {2p, 2p+1}
    const int t    = threadIdx.x;
    const int wv   = t >> 6;          // wave 0..15
    const int lane = t & 63;
    const int Q    = lane & 15;
    const int GG   = lane >> 4;
    int step = 1, dcnt = 0;

    // init both h layouts from h0
    #pragma unroll
    for (int s = 0; s < 2; ++s) {
        float4 v = *(const float4*)&h0[(size_t)(2 * p + s) * 4096 + t * 4];
        int c = t >> 4, i0 = (t & 15) * 4;
        *(float4*)&HC[s * 4352 + c * 68 + i0] = v;
        HT[s * 4096 + (i0 + 0) * 64 + c] = v.x;
        HT[s * 4096 + (i0 + 1) * 64 + c] = v.y;
        HT[s * 4096 + (i0 + 2) * 64 + c] = v.z;
        HT[s * 4096 + (i0 + 3) * 64 + c] = v.w;
    }

    auto layer = [&](auto finc, const float* __restrict__ WT,
                     const float* __restrict__ Gm,
                     const float* __restrict__ gbp,
                     const float* __restrict__ bb2p,
                     const float* __restrict__ biasp,
                     const float* __restrict__ bsrc,
                     const float* __restrict__ den0p, bool entry) {
        constexpr bool FIN = decltype(finc)::value;
        const int o   = FIN ? wv : q * 16 + wv;
        const bool act = !FIN || wv < 10;
        const int row0 = (wv * 2) * 64, row1 = (wv * 2 + 1) * 64;

        // prologue: issue all layer-invariant + logit loads BEFORE the spin
        float bl0 = 0.f, bl1 = 0.f, bb2o = 0.f;
        float4 gbv4 = make_float4(0.f, 0.f, 0.f, 0.f);
        float4 bias4 = gbv4;
        const float* pG  = Gm;
        const float* pWT = WT;
        if (act) {
            pG  = Gm + o * 4096 + GG * 64 + 4 * Q;
            pWT = WT + o * 4096 + GG * 64 + 4 * Q;
            gbv4 = *(const float4*)&gbp[o * 64 + 4 * Q];
            bb2o = bb2p[o];
            bias4 = *(const float4*)&biasp[o * 64 + 4 * Q];
            if (FIN) {
                bl0 = b_cls[(size_t)(2 * p) * 640 + o * 64 + lane];
                bl1 = b_cls[(size_t)(2 * p + 1) * 640 + o * 64 + lane];
            } else {
                bl0 = bsrc[o * 64 + lane];
                bl1 = bsrc[4096 + o * 64 + lane];
            }
        }

        // ---- layer entry: partner HC/HT fill (spin overlapped w/ loads) ---
        if (entry) {
            if (t < 3) {
                int qq = t + (t >= q);
                while (SYS_LD(&flags[(qq * 64 + p) * 16]) < step) {}
            }
            __syncthreads();
            #pragma unroll
            for (int j = 0; j < 3; ++j) {
                int qq = j + (j >= q);
                const float* vp = vbuf + (size_t)(qq * 64 + p) * 2048;
                #pragma unroll
                for (int rep = 0; rep < 2; ++rep) {
                    int idx = rep * 1024 + t;
                    int d = idx & 63, s = (idx >> 6) & 1, ol = idx >> 7;
                    float v = SYS_LD(&vp[idx]);
                    HC[s * 4352 + d * 68 + qq * 16 + ol] = v;
                    HT[s * 4096 + (qq * 16 + ol) * 64 + d] = v;
                }
            }
            ++step;
            __syncthreads();
        } else {
            __syncthreads();   // HC/HT init (layer 0) complete
        }

        for (int it = 0; it < 3; ++it) {
            // ---- softmax denominator ----
            float cc0 = 0.f, cc1 = 0.f, bp0 = 1.f, bp1 = 1.f;
            if (act) { cc0 = expf(bl0); cc1 = expf(bl1); }
            if (it == 0 && !FIN) {
                if (act) { bp0 = den0p[lane]; bp1 = den0p[64 + lane]; }
            } else {
                PP[wv * 64 + lane] = cc0;
                PP[1024 + wv * 64 + lane] = cc1;
                __syncthreads();
                bp0 = 0.f; bp1 = 0.f;
                #pragma unroll
                for (int w = 0; w < 16; ++w) {
                    bp0 += PP[w * 64 + lane];
                    bp1 += PP[1024 + w * 64 + lane];
                }
                if (!FIN) {      // 4-way partner exchange (SYS scope)
                    float* xb = xbuf + ((size_t)(dcnt & 1) * 256 + B) * 128;
                    if (wv == 0) {
                        SYS_ST(&xb[lane], bp0);
                        SYS_ST(&xb[64 + lane], bp1);
                        asm volatile("s_waitcnt vmcnt(0)" ::: "memory");
                        if (lane == 0) SYS_ST(&flags[B * 16], step);
                        if (lane < 3) {
                            int qq = lane + (lane >= q);
                            while (SYS_LD(&flags[(qq * 64 + p) * 16]) < step) {}
                        }
                    }
                    __syncthreads();
                    #pragma unroll
                    for (int j = 0; j < 3; ++j) {
                        int qq = j + (j >= q);
                        const float* xp = xbuf + ((size_t)(dcnt & 1) * 256 + qq * 64 + p) * 128;
                        bp0 += SYS_LD(&xp[lane]);
                        bp1 += SYS_LD(&xp[64 + lane]);
                    }
                    ++step; ++dcnt;
                }
            }
            float sc0 = 0.f, sc1 = 0.f;
            if (act) {
                float cv0 = cc0 / bp0, cv1 = cc1 / bp1;
                CC[row0 + lane] = cv0;
                CC[row1 + lane] = cv1;
                float a0 = cv0, a1 = cv1;
                #pragma unroll
                for (int m = 1; m < 64; m <<= 1) {
                    a0 += __shfl_xor(a0, m, 64);
                    a1 += __shfl_xor(a1, m, 64);
                }
                sc0 = a0; sc1 = a1;
            }
            __builtin_amdgcn_wave_barrier();

            // ---- Y: y[c=lane] = sum_i c[i] h[c][i] via HT columns (b32) ----
            float y0 = 0.f, y1 = 0.f;
            if (act) {
                #pragma unroll 8
                for (int k = 0; k < 16; ++k) {
                    float4 c40 = *(const float4*)&CC[row0 + 4 * k];
                    float4 c41 = *(const float4*)&CC[row1 + 4 * k];
                    const float* hp0 = &HT[(4 * k) * 64 + lane];
                    const float* hp1 = &HT[4096 + (4 * k) * 64 + lane];
                    y0 = fmaf(c40.x, hp0[0],   y0);
                    y0 = fmaf(c40.y, hp0[64],  y0);
                    y0 = fmaf(c40.z, hp0[128], y0);
                    y0 = fmaf(c40.w, hp0[192], y0);
                    y1 = fmaf(c41.x, hp1[0],   y1);
                    y1 = fmaf(c41.y, hp1[64],  y1);
                    y1 = fmaf(c41.z, hp1[128], y1);
                    y1 = fmaf(c41.w, hp1[192], y1);
                }
            }
            __builtin_amdgcn_wave_barrier();
            if (act) { CC[row0 + lane] = y0; CC[row1 + lane] = y1; }   // y rows
            __builtin_amdgcn_wave_barrier();

            if (it < 2) {
                // ---- GY: stream G once, FMA both samples ----
                float4 a0 = make_float4(0.f, 0.f, 0.f, 0.f), a1 = a0;
                if (act) {
                    #pragma unroll 8
                    for (int k = 0; k < 16; ++k) {
                        float4 w4 = *(const float4*)&pG[k << 8];
                        float yb0 = CC[row0 + 4 * k + GG];
                        float yb1 = CC[row1 + 4 * k + GG];
                        a0.x = fmaf(w4.x, yb0, a0.x); a0.y = fmaf(w4.y, yb0, a0.y);
                        a0.z = fmaf(w4.z, yb0, a0.z); a0.w = fmaf(w4.w, yb0, a0.w);
                        a1.x = fmaf(w4.x, yb1, a1.x); a1.y = fmaf(w4.y, yb1, a1.y);
                        a1.z = fmaf(w4.z, yb1, a1.z); a1.w = fmaf(w4.w, yb1, a1.w);
                    }
                    #pragma unroll
                    for (int m = 16; m <= 32; m <<= 1) {
                        a0.x += __shfl_xor(a0.x, m, 64); a0.y += __shfl_xor(a0.y, m, 64);
                        a0.z += __shfl_xor(a0.z, m, 64); a0.w += __shfl_xor(a0.w, m, 64);
                        a1.x += __shfl_xor(a1.x, m, 64); a1.y += __shfl_xor(a1.y, m, 64);
                        a1.z += __shfl_xor(a1.z, m, 64); a1.w += __shfl_xor(a1.w, m, 64);
                    }
                }
                float vd0 = 0.f, vd1 = 0.f;
                if (act) {
                    float4 y40 = *(const float4*)&CC[row0 + 4 * Q];
                    float4 y41 = *(const float4*)&CC[row1 + 4 * Q];
                    float n20 = y40.x * a0.x + y40.y * a0.y + y40.z * a0.z + y40.w * a0.w;
                    float n21 = y41.x * a1.x + y41.y * a1.y + y41.z * a1.z + y41.w * a1.w;
                    float yg0 = y40.x * gbv4.x + y40.y * gbv4.y + y40.z * gbv4.z + y40.w * gbv4.w;
                    float yg1 = y41.x * gbv4.x + y41.y * gbv4.y + y41.z * gbv4.z + y41.w * gbv4.w;
                    #pragma unroll
                    for (int m = 1; m <= 8; m <<= 1) {
                        n20 += __shfl_xor(n20, m, 64);
                        n21 += __shfl_xor(n21, m, 64);
                        yg0 += __shfl_xor(yg0, m, 64);
                        yg1 += __shfl_xor(yg1, m, 64);
                    }
                    n20 = n20 + 2.f * sc0 * yg0 + sc0 * sc0 * bb2o;
                    n21 = n21 + 2.f * sc1 * yg1 + sc1 * sc1 * bb2o;
                    float s0 = (n20 / (1.f + n20)) * rsqrtf(n20 + 1e-8f);
                    float s1 = (n21 / (1.f + n21)) * rsqrtf(n21 + 1e-8f);
                    vd0 = s0 * (yg0 + sc0 * bb2o);
                    vd1 = s1 * (yg1 + sc1 * bb2o);
                    if (GG == 0) {
                        float4 u0, u1;
                        u0.x = s0 * (a0.x + sc0 * gbv4.x); u0.y = s0 * (a0.y + sc0 * gbv4.y);
                        u0.z = s0 * (a0.z + sc0 * gbv4.z); u0.w = s0 * (a0.w + sc0 * gbv4.w);
                        u1.x = s1 * (a1.x + sc1 * gbv4.x); u1.y = s1 * (a1.y + sc1 * gbv4.y);
                        u1.z = s1 * (a1.z + sc1 * gbv4.z); u1.w = s1 * (a1.w + sc1 * gbv4.w);
                        *(float4*)&CC[row0 + 4 * Q] = u0;   // u rows
                        *(float4*)&CC[row1 + 4 * Q] = u1;
                    }
                }
                __builtin_amdgcn_wave_barrier();

                // ---- DB: db[i] = sum_c u[c] h[c][i] via HC ----
                if (act) {
                    float4 d0 = make_float4(0.f, 0.f, 0.f, 0.f), d1 = d0;
                    #pragma unroll 8
                    for (int k = 0; k < 16; ++k) {
                        int c = 4 * k + GG;
                        float4 hc0 = *(const float4*)&HC[c * 68 + 4 * Q];
                        float ub0 = CC[row0 + c];
                        d0.x = fmaf(ub0, hc0.x, d0.x); d0.y = fmaf(ub0, hc0.y, d0.y);
                        d0.z = fmaf(ub0, hc0.z, d0.z); d0.w = fmaf(ub0, hc0.w, d0.w);
                        float4 hc1 = *(const float4*)&HC[4352 + c * 68 + 4 * Q];
                        float ub1 = CC[row1 + c];
                        d1.x = fmaf(ub1, hc1.x, d1.x); d1.y = fmaf(ub1, hc1.y, d1.y);
                        d1.z = fmaf(ub1, hc1.z, d1.z); d1.w = fmaf(ub1, hc1.w, d1.w);
                    }
                    #pragma unroll
                    for (int m = 16; m <= 32; m <<= 1) {
                        d0.x += __shfl_xor(d0.x, m, 64); d0.y += __shfl_xor(d0.y, m, 64);
                        d0.z += __shfl_xor(d0.z, m, 64); d0.w += __shfl_xor(d0.w, m, 64);
                        d1.x += __shfl_xor(d1.x, m, 64); d1.y += __shfl_xor(d1.y, m, 64);
                        d1.z += __shfl_xor(d1.z, m, 64); d1.w += __shfl_xor(d1.w, m, 64);
                    }
                    if (GG == 0) {
                        *(float4*)&CC[row0 + 4 * Q] = d0;
                        *(float4*)&CC[row1 + 4 * Q] = d1;
                    }
                }
                __builtin_amdgcn_wave_barrier();
                if (act) {
                    bl0 += CC[row0 + lane] + vd0;
                    bl1 += CC[row1 + lane] + vd1;
                }
            } else {
                // ---- iter 2: S via WT, squash, output v ----
                if (act) {
                    float4 s40 = make_float4(0.f, 0.f, 0.f, 0.f), s41 = s40;
                    #pragma unroll 8
                    for (int k = 0; k < 16; ++k) {
                        float4 w4 = *(const float4*)&pWT[k << 8];
                        float yb0 = CC[row0 + 4 * k + GG];
                        float yb1 = CC[row1 + 4 * k + GG];
                        s40.x = fmaf(w4.x, yb0, s40.x); s40.y = fmaf(w4.y, yb0, s40.y);
                        s40.z = fmaf(w4.z, yb0, s40.z); s40.w = fmaf(w4.w, yb0, s40.w);
                        s41.x = fmaf(w4.x, yb1, s41.x); s41.y = fmaf(w4.y, yb1, s41.y);
                        s41.z = fmaf(w4.z, yb1, s41.z); s41.w = fmaf(w4.w, yb1, s41.w);
                    }
                    #pragma unroll
                    for (int m = 16; m <= 32; m <<= 1) {
                        s40.x += __shfl_xor(s40.x, m, 64); s40.y += __shfl_xor(s40.y, m, 64);
                        s40.z += __shfl_xor(s40.z, m, 64); s40.w += __shfl_xor(s40.w, m, 64);
                        s41.x += __shfl_xor(s41.x, m, 64); s41.y += __shfl_xor(s41.y, m, 64);
                        s41.z += __shfl_xor(s41.z, m, 64); s41.w += __shfl_xor(s41.w, m, 64);
                    }
                    s40.x = fmaf(bias4.x, sc0, s40.x); s40.y = fmaf(bias4.y, sc0, s40.y);
                    s40.z = fmaf(bias4.z, sc0, s40.z); s40.w = fmaf(bias4.w, sc0, s40.w);
                    s41.x = fmaf(bias4.x, sc1, s41.x); s41.y = fmaf(bias4.y, sc1, s41.y);
                    s41.z = fmaf(bias4.z, sc1, s41.z); s41.w = fmaf(bias4.w, sc1, s41.w);
                    float n20 = s40.x * s40.x + s40.y * s40.y + s40.z * s40.z + s40.w * s40.w;
                    float n21 = s41.x * s41.x + s41.y * s41.y + s41.z * s41.z + s41.w * s41.w;
                    #pragma unroll
                    for (int m = 1; m <= 8; m <<= 1) {
                        n20 += __shfl_xor(n20, m, 64);
                        n21 += __shfl_xor(n21, m, 64);
                    }
                    float sl0 = (n20 / (1.f + n20)) * rsqrtf(n20 + 1e-8f);
                    float sl1 = (n21 / (1.f + n21)) * rsqrtf(n21 + 1e-8f);
                    float4 v0, v1;
                    v0.x = s40.x * sl0; v0.y = s40.y * sl0; v0.z = s40.z * sl0; v0.w = s40.w * sl0;
                    v1.x = s41.x * sl1; v1.y = s41.y * sl1; v1.z = s41.z * sl1; v1.w = s41.w * sl1;
                    if (FIN) {
                        if (q == 0 && GG == 0) {
                            *(float4*)&out[(size_t)(2 * p) * 640 + o * 64 + 4 * Q] = v0;
                            *(float4*)&out[(size_t)(2 * p + 1) * 640 + o * 64 + 4 * Q] = v1;
                        }
                    } else if (GG == 0) {
                        *(float4*)&CC[row0 + 4 * Q] = v0;   // v rows
                        *(float4*)&CC[row1 + 4 * Q] = v1;
                    }
                }
            }
        }

        // ---- layer epilogue (non-FIN): post v, rebuild OWN quarter ----
        if (!FIN) {
            __syncthreads();     // all v rows final in CC
            float* vb = vbuf + (size_t)B * 2048;
            if (t < 512)
                sys_st4(&vb[t * 4], *(const float4*)&CC[t * 4]);
            asm volatile("s_waitcnt vmcnt(0)" ::: "memory");
            __syncthreads();     // all waves' stores drained
            if (t == 0) SYS_ST(&flags[B * 16], step);
            // own 16 o's from CC while partners catch up
            #pragma unroll
            for (int rep = 0; rep < 2; ++rep) {
                int idx = rep * 1024 + t;
                int d = idx & 63, s = (idx >> 6) & 1, ol = idx >> 7;
                float v = CC[idx];
                HC[s * 4352 + d * 68 + q * 16 + ol] = v;
                HT[s * 4096 + (q * 16 + ol) * 64 + d] = v;
            }
            __syncthreads();     // CC free for next layer's c rows
        }
    };

    layer(std::integral_constant<bool, false>{}, WT1, G1, gb1, bb21, b1,
          b_basic + (((size_t)0 * 128 + 2 * p) << 12),
          den0 + ((size_t)0 * 128 + 2 * p) * 64, false);
    layer(std::integral_constant<bool, false>{}, WT1, G1, gb1, bb21, b1,
          b_basic + (((size_t)1 * 128 + 2 * p) << 12),
          den0 + ((size_t)1 * 128 + 2 * p) * 64, true);
    layer(std::integral_constant<bool, false>{}, WT1, G1, gb1, bb21, b1,
          b_basic + (((size_t)2 * 128 + 2 * p) << 12),
          den0 + ((size_t)2 * 128 + 2 * p) * 64, true);
    layer(std::integral_constant<bool, true>{}, WT2, G2, gb2, bb22, b2,
          nullptr, nullptr, true);
}

extern "C" void kernel_launch(void* const* d_in, const int* in_sizes, int n_in,
                              void* d_out, int out_size, void* d_ws, size_t ws_size,
                              hipStream_t stream) {
    const float* x       = (const float*)d_in[0];
    const float* Wb      = (const float*)d_in[1];
    const float* bb      = (const float*)d_in[2];
    const float* W1      = (const float*)d_in[3];
    const float* b1      = (const float*)d_in[4];
    const float* W2      = (const float*)d_in[5];
    const float* b2      = (const float*)d_in[6];
    const float* b_basic = (const float*)d_in[7];
    const float* b_cls   = (const float*)d_in[8];
    float* out = (float*)d_out;

    float* h0    = (float*)d_ws;             // [128,64,64]   524288 f
    float* WT1   = h0   + 524288;            // [64,64,64]    262144
    float* WT2   = WT1  + 262144;            // [10,64,64]    40960
    float* G1    = WT2  + 40960;             // [64,64,64]    262144
    float* G2    = G1   + 262144;            // [10,64,64]    40960
    float* gb1   = G2   + 40960;             // [64,64]       4096
    float* gb2   = gb1  + 4096;              // [10,64]       640
    float* bb21  = gb2  + 640;               // [64]          64
    float* bb22  = bb21 + 64;                // [16]          16
    float* den0  = bb22 + 16;                // [3,128,64]    24576
    float* xbuf  = den0 + 24576;             // [2][256][128] 65536
    float* vbuf  = xbuf + 65536;             // [256][2048]   524288
    int*   flags = (int*)(vbuf + 524288);    // [4096]

    prep_kernel<<<379, 512, 0, stream>>>(x, Wb, bb, W1, b1, W2, b2, b_basic,
                                         h0, WT1, G1, gb1, bb21,
                                         WT2, G2, gb2, bb22, den0, flags);
    caps_fused<<<256, 1024, 0, stream>>>(h0, WT1, G1, gb1, bb21, b1,
                                         WT2, G2, gb2, bb22, b2,
                                         b_basic, b_cls, den0,
                                         xbuf, vbuf, flags, out);
}

// Round 15
// 136.087 us; speedup vs baseline: 1.0419x; 1.0419x over previous
//
#include <hip/hip_runtime.h>
#include <math.h>
#include <type_traits>

// ---------------------------------------------------------------------------
// CapsNet forward, fused routing, Gram-trick + 2-sample W amortization.
//   iters 0,1 per (b,o):  y=Hc;  n2=yGy+2sc(y.gb)+sc^2 bb2;  u=scale(Gy+sc gb)
//   iter 2 streams WT for v.  Blocks: 256 = 4 o-quarters x 64 sample-pairs.
// Round-15 (consolidation): round-13's caps_fused (measured 128.0 us; the
// HC-only layout beat the r14 dual-layout "fix" — wave64 b128 LDS reads are
// >=8 cycles by bandwidth, so the 8-way pattern was mostly not fixable) +
// round-14's prep (measured ~8.3 us overhead; hw-half conv split).
// ---------------------------------------------------------------------------

#define SYS_ST(p, v) __hip_atomic_store((p), (v), __ATOMIC_RELAXED, __HIP_MEMORY_SCOPE_SYSTEM)
#define SYS_LD(p)    __hip_atomic_load((p), __ATOMIC_RELAXED, __HIP_MEMORY_SCOPE_SYSTEM)

typedef float v4f __attribute__((ext_vector_type(4)));

__device__ __forceinline__ void sys_st4(float* p, float4 q) {
    v4f v; v[0] = q.x; v[1] = q.y; v[2] = q.z; v[3] = q.w;
    asm volatile("global_store_dwordx4 %0, %1, off sc0 sc1" :: "v"(p), "v"(v) : "memory");
}

// blocks 0-63: W1 o-prep | 64-73: W2 o-prep | 74-121: den0 | 122: flags |
// 123-378: conv+squash (sample b = id>>1, hw-half hh = id&1)
__global__ __launch_bounds__(512) void prep_kernel(
    const float* __restrict__ x, const float* __restrict__ Wb,
    const float* __restrict__ bb,
    const float* __restrict__ W1, const float* __restrict__ b1,
    const float* __restrict__ W2, const float* __restrict__ b2,
    const float* __restrict__ b_basic,
    float* __restrict__ h,
    float* __restrict__ WT1, float* __restrict__ G1,
    float* __restrict__ gb1, float* __restrict__ bb21,
    float* __restrict__ WT2, float* __restrict__ G2,
    float* __restrict__ gb2, float* __restrict__ bb22,
    float* __restrict__ den0, int* __restrict__ flags)
{
    __shared__ float smem[8480];
    const int blk = blockIdx.x;
    const int t = threadIdx.x;

    if (blk < 74) {
        // ------------- per-o W prep (proven 256-thread code, t<256) -------
        const bool w1 = blk < 64;
        const int o = w1 ? blk : (blk - 64);
        const float* W    = w1 ? W1 : W2;
        const float* bias = w1 ? b1 : b2;
        float* WT  = w1 ? WT1  : WT2;
        float* G   = w1 ? G1   : G2;
        float* gb  = w1 ? gb1  : gb2;
        float* bb2 = w1 ? bb21 : bb22;
        float* WS = smem;                 // [64][68] = W_o as [d][c]
        if (t < 256) {
            #pragma unroll
            for (int p = 0; p < 4; ++p) {
                int idx = t + p * 256;
                int d = idx >> 4, c0 = (idx & 15) * 4;
                *(float4*)&WS[d * 68 + c0] =
                    *(const float4*)&W[((size_t)o * 64 + d) * 64 + c0];
            }
        }
        __syncthreads();
        if (t < 256) {
            {   // transpose WT[o][c][d]
                const int Q = t & 15, R = t >> 4;
                #pragma unroll
                for (int p = 0; p < 4; ++p) {
                    int c = R + 16 * p;
                    float4 v;
                    v.x = WS[(4 * Q + 0) * 68 + c];
                    v.y = WS[(4 * Q + 1) * 68 + c];
                    v.z = WS[(4 * Q + 2) * 68 + c];
                    v.w = WS[(4 * Q + 3) * 68 + c];
                    *(float4*)&WT[((size_t)o * 64 + c) * 64 + 4 * Q] = v;
                }
            }
            {   // Gram
                const int c1 = t >> 2, j = t & 3;
                float acc[16];
                #pragma unroll
                for (int g = 0; g < 16; ++g) acc[g] = 0.f;
                for (int d = 0; d < 64; ++d) {
                    float a = WS[d * 68 + c1];
                    #pragma unroll
                    for (int g = 0; g < 16; ++g)
                        acc[g] = fmaf(a, WS[d * 68 + j * 16 + g], acc[g]);
                }
                #pragma unroll
                for (int g = 0; g < 16; ++g)
                    G[(size_t)o * 4096 + c1 * 64 + j * 16 + g] = acc[g];
            }
            if (t < 64) {
                float s = 0.f;
                for (int d = 0; d < 64; ++d) s = fmaf(bias[o * 64 + d], WS[d * 68 + t], s);
                gb[o * 64 + t] = s;
            }
            if (t == 0) {
                float s = 0.f;
                for (int d = 0; d < 64; ++d) { float bv = bias[o * 64 + d]; s = fmaf(bv, bv, s); }
                bb2[o] = s;
            }
        }
    } else if (blk < 122) {
        const int g = (blk - 74) * 512 + t;        // 24576 total
        const int L = g >> 13, b = (g >> 6) & 127, i = g & 63;
        const float* bp = b_basic + (((size_t)L * 128 + b) << 12) + i;
        float s = 0.f;
        for (int o = 0; o < 64; ++o) s += expf(bp[o * 64]);
        den0[((size_t)L * 128 + b) * 64 + i] = s;
    } else if (blk == 122) {
        for (int i = t; i < 4096; i += 512) flags[i] = 0;
    } else {
        // -------- conv3x3+bias+ReLU+channel-squash, hw-half per block -----
        float* xs  = smem;            // [64][100] padded
        float* hs  = smem + 6400;     // [64][32]  (this half's hw)
        float* scl = smem + 8448;     // [32]
        const int id = blk - 123;
        const int b = id >> 1, hh = id & 1;
        for (int idx = t; idx < 6400; idx += 512) xs[idx] = 0.f;
        __syncthreads();
        #pragma unroll
        for (int k2 = 0; k2 < 2; ++k2) {
            int idx4 = t + k2 * 512;
            float4 v = *(const float4*)&x[(size_t)b * 4096 + idx4 * 4];
            int e0 = idx4 * 4;
            int c  = e0 >> 6;
            int hw = e0 & 63;
            int r = hw >> 3, cc = hw & 7;
            float* xp = &xs[c * 100 + (r + 1) * 10 + (cc + 1)];
            xp[0] = v.x; xp[1] = v.y; xp[2] = v.z; xp[3] = v.w;
        }
        __syncthreads();
        const int oc = t >> 3;        // 0..63, 8 threads per oc
        const int hg = t & 7;         // 4 hw each within the half
        float acc[4] = {0.f, 0.f, 0.f, 0.f};
        const float* wp = Wb + (size_t)oc * 576;
        for (int ic = 0; ic < 64; ++ic) {
            float w[9];
            #pragma unroll
            for (int j = 0; j < 9; ++j) w[j] = wp[ic * 9 + j];
            const float* xr = &xs[ic * 100];
            #pragma unroll
            for (int k = 0; k < 4; ++k) {
                int hw = hh * 32 + hg * 4 + k;
                int r = hw >> 3, cc = hw & 7;
                int p0 = r * 10 + cc;
                float a = acc[k];
                a = fmaf(w[0], xr[p0],      a);
                a = fmaf(w[1], xr[p0 + 1],  a);
                a = fmaf(w[2], xr[p0 + 2],  a);
                a = fmaf(w[3], xr[p0 + 10], a);
                a = fmaf(w[4], xr[p0 + 11], a);
                a = fmaf(w[5], xr[p0 + 12], a);
                a = fmaf(w[6], xr[p0 + 20], a);
                a = fmaf(w[7], xr[p0 + 21], a);
                a = fmaf(w[8], xr[p0 + 22], a);
                acc[k] = a;
            }
        }
        float bias = bb[oc];
        #pragma unroll
        for (int k = 0; k < 4; ++k) {
            float v = acc[k] + bias;
            hs[oc * 32 + hg * 4 + k] = v > 0.f ? v : 0.f;
        }
        __syncthreads();
        if (t < 32) {
            float n2 = 0.f;
            for (int c = 0; c < 64; ++c) { float v = hs[c * 32 + t]; n2 = fmaf(v, v, n2); }
            scl[t] = (n2 / (1.f + n2)) * rsqrtf(n2 + 1e-8f);
        }
        __syncthreads();
        {
            float4 o;
            o.x = hs[oc * 32 + hg * 4 + 0] * scl[hg * 4 + 0];
            o.y = hs[oc * 32 + hg * 4 + 1] * scl[hg * 4 + 1];
            o.z = hs[oc * 32 + hg * 4 + 2] * scl[hg * 4 + 2];
            o.w = hs[oc * 32 + hg * 4 + 3] * scl[hg * 4 + 3];
            *(float4*)&h[(size_t)b * 4096 + oc * 64 + hh * 32 + hg * 4] = o;
        }
    }
}

__global__ __launch_bounds__(1024, 4) void caps_fused(
    const float* __restrict__ h0,
    const float* __restrict__ WT1, const float* __restrict__ G1,
    const float* __restrict__ gb1, const float* __restrict__ bb21,
    const float* __restrict__ b1,
    const float* __restrict__ WT2, const float* __restrict__ G2,
    const float* __restrict__ gb2, const float* __restrict__ bb22,
    const float* __restrict__ b2,
    const float* __restrict__ b_basic, const float* __restrict__ b_cls,
    const float* __restrict__ den0,
    float* __restrict__ xbuf,   // [2][256][128]  den partial ping-pong
    float* __restrict__ vbuf,   // [256][2048]    layer-end v chunks
    int*   __restrict__ flags,  // [256*16]
    float* __restrict__ out)
{
    __shared__ float HC[8704];    // [2][64][68]  h as [c][i]
    __shared__ float CC[2048];    // [32 rows][64] per-(o,s) comm rows
    __shared__ float PP[10240];   // [2][16][64] used + pad (forces 1 blk/CU)

    const int B    = blockIdx.x;      // 0..255
    const int q    = B >> 6;          // o-quarter 0..3
    const int p    = B & 63;          // sample-pair; samples {2p, 2p+1}
    const int t    = threadIdx.x;
    const int wv   = t >> 6;          // wave 0..15
    const int lane = t & 63;
    const int Q    = lane & 15;
    const int GG   = lane >> 4;
    int step = 1, dcnt = 0;

    // init HC[s][c][i] from h0
    #pragma unroll
    for (int s = 0; s < 2; ++s) {
        float4 v = *(const float4*)&h0[(size_t)(2 * p + s) * 4096 + t * 4];
        int c = t >> 4, i0 = (t & 15) * 4;
        *(float4*)&HC[s * 4352 + c * 68 + i0] = v;
    }

    auto layer = [&](auto finc, const float* __restrict__ WT,
                     const float* __restrict__ Gm,
                     const float* __restrict__ gbp,
                     const float* __restrict__ bb2p,
                     const float* __restrict__ biasp,
                     const float* __restrict__ bsrc,
                     const float* __restrict__ den0p, bool entry) {
        constexpr bool FIN = decltype(finc)::value;
        const int o   = FIN ? wv : q * 16 + wv;
        const bool act = !FIN || wv < 10;
        const int row0 = (wv * 2) * 64, row1 = (wv * 2 + 1) * 64;

        // prologue: issue all layer-invariant + logit loads BEFORE the spin
        float bl0 = 0.f, bl1 = 0.f, bb2o = 0.f;
        float4 gbv4 = make_float4(0.f, 0.f, 0.f, 0.f);
        float4 bias4 = gbv4;
        const float* pG  = Gm;
        const float* pWT = WT;
        if (act) {
            pG  = Gm + o * 4096 + GG * 64 + 4 * Q;
            pWT = WT + o * 4096 + GG * 64 + 4 * Q;
            gbv4 = *(const float4*)&gbp[o * 64 + 4 * Q];
            bb2o = bb2p[o];
            bias4 = *(const float4*)&biasp[o * 64 + 4 * Q];
            if (FIN) {
                bl0 = b_cls[(size_t)(2 * p) * 640 + o * 64 + lane];
                bl1 = b_cls[(size_t)(2 * p + 1) * 640 + o * 64 + lane];
            } else {
                bl0 = bsrc[o * 64 + lane];
                bl1 = bsrc[4096 + o * 64 + lane];
            }
        }

        // ---- layer entry: partner HC fill (spin overlapped with loads) ----
        if (entry) {
            if (t < 3) {
                int qq = t + (t >= q);
                while (SYS_LD(&flags[(qq * 64 + p) * 16]) < step) {}
            }
            __syncthreads();
            #pragma unroll
            for (int j = 0; j < 3; ++j) {
                int qq = j + (j >= q);
                const float* vp = vbuf + (size_t)(qq * 64 + p) * 2048;
                #pragma unroll
                for (int rep = 0; rep < 2; ++rep) {
                    int idx = rep * 1024 + t;
                    int d = idx & 63, s = (idx >> 6) & 1, ol = idx >> 7;
                    HC[s * 4352 + d * 68 + qq * 16 + ol] = SYS_LD(&vp[idx]);
                }
            }
            ++step;
            __syncthreads();
        } else {
            __syncthreads();   // HC init (layer 0) complete
        }

        for (int it = 0; it < 3; ++it) {
            // ---- softmax denominator ----
            float cc0 = 0.f, cc1 = 0.f, bp0 = 1.f, bp1 = 1.f;
            if (act) { cc0 = expf(bl0); cc1 = expf(bl1); }
            if (it == 0 && !FIN) {
                if (act) { bp0 = den0p[lane]; bp1 = den0p[64 + lane]; }
            } else {
                PP[wv * 64 + lane] = cc0;
                PP[1024 + wv * 64 + lane] = cc1;
                __syncthreads();
                bp0 = 0.f; bp1 = 0.f;
                #pragma unroll
                for (int w = 0; w < 16; ++w) {
                    bp0 += PP[w * 64 + lane];
                    bp1 += PP[1024 + w * 64 + lane];
                }
                if (!FIN) {      // 4-way partner exchange (SYS scope)
                    float* xb = xbuf + ((size_t)(dcnt & 1) * 256 + B) * 128;
                    if (wv == 0) {
                        SYS_ST(&xb[lane], bp0);
                        SYS_ST(&xb[64 + lane], bp1);
                        asm volatile("s_waitcnt vmcnt(0)" ::: "memory");
                        if (lane == 0) SYS_ST(&flags[B * 16], step);
                        if (lane < 3) {
                            int qq = lane + (lane >= q);
                            while (SYS_LD(&flags[(qq * 64 + p) * 16]) < step) {}
                        }
                    }
                    __syncthreads();
                    #pragma unroll
                    for (int j = 0; j < 3; ++j) {
                        int qq = j + (j >= q);
                        const float* xp = xbuf + ((size_t)(dcnt & 1) * 256 + qq * 64 + p) * 128;
                        bp0 += SYS_LD(&xp[lane]);
                        bp1 += SYS_LD(&xp[64 + lane]);
                    }
                    ++step; ++dcnt;
                }
            }
            float sc0 = 0.f, sc1 = 0.f;
            if (act) {
                float cv0 = cc0 / bp0, cv1 = cc1 / bp1;
                CC[row0 + lane] = cv0;
                CC[row1 + lane] = cv1;
                float a0 = cv0, a1 = cv1;
                #pragma unroll
                for (int m = 1; m < 64; m <<= 1) {
                    a0 += __shfl_xor(a0, m, 64);
                    a1 += __shfl_xor(a1, m, 64);
                }
                sc0 = a0; sc1 = a1;
            }
            __builtin_amdgcn_wave_barrier();

            // ---- Y: y[c=lane] = sum_i c[i] h[c][i] (both samples) ----
            float y0 = 0.f, y1 = 0.f;
            if (act) {
                #pragma unroll 8
                for (int k = 0; k < 16; ++k) {
                    float4 h40 = *(const float4*)&HC[lane * 68 + 4 * k];
                    float4 c40 = *(const float4*)&CC[row0 + 4 * k];
                    y0 = fmaf(h40.x, c40.x, y0); y0 = fmaf(h40.y, c40.y, y0);
                    y0 = fmaf(h40.z, c40.z, y0); y0 = fmaf(h40.w, c40.w, y0);
                    float4 h41 = *(const float4*)&HC[4352 + lane * 68 + 4 * k];
                    float4 c41 = *(const float4*)&CC[row1 + 4 * k];
                    y1 = fmaf(h41.x, c41.x, y1); y1 = fmaf(h41.y, c41.y, y1);
                    y1 = fmaf(h41.z, c41.z, y1); y1 = fmaf(h41.w, c41.w, y1);
                }
            }
            __builtin_amdgcn_wave_barrier();
            if (act) { CC[row0 + lane] = y0; CC[row1 + lane] = y1; }   // y rows
            __builtin_amdgcn_wave_barrier();

            if (it < 2) {
                // ---- GY: stream G once, FMA both samples ----
                float4 a0 = make_float4(0.f, 0.f, 0.f, 0.f), a1 = a0;
                if (act) {
                    #pragma unroll 8
                    for (int k = 0; k < 16; ++k) {
                        float4 w4 = *(const float4*)&pG[k << 8];
                        float yb0 = CC[row0 + 4 * k + GG];
                        float yb1 = CC[row1 + 4 * k + GG];
                        a0.x = fmaf(w4.x, yb0, a0.x); a0.y = fmaf(w4.y, yb0, a0.y);
                        a0.z = fmaf(w4.z, yb0, a0.z); a0.w = fmaf(w4.w, yb0, a0.w);
                        a1.x = fmaf(w4.x, yb1, a1.x); a1.y = fmaf(w4.y, yb1, a1.y);
                        a1.z = fmaf(w4.z, yb1, a1.z); a1.w = fmaf(w4.w, yb1, a1.w);
                    }
                    #pragma unroll
                    for (int m = 16; m <= 32; m <<= 1) {
                        a0.x += __shfl_xor(a0.x, m, 64); a0.y += __shfl_xor(a0.y, m, 64);
                        a0.z += __shfl_xor(a0.z, m, 64); a0.w += __shfl_xor(a0.w, m, 64);
                        a1.x += __shfl_xor(a1.x, m, 64); a1.y += __shfl_xor(a1.y, m, 64);
                        a1.z += __shfl_xor(a1.z, m, 64); a1.w += __shfl_xor(a1.w, m, 64);
                    }
                }
                float vd0 = 0.f, vd1 = 0.f;
                if (act) {
                    float4 y40 = *(const float4*)&CC[row0 + 4 * Q];
                    float4 y41 = *(const float4*)&CC[row1 + 4 * Q];
                    float n20 = y40.x * a0.x + y40.y * a0.y + y40.z * a0.z + y40.w * a0.w;
                    float n21 = y41.x * a1.x + y41.y * a1.y + y41.z * a1.z + y41.w * a1.w;
                    float yg0 = y40.x * gbv4.x + y40.y * gbv4.y + y40.z * gbv4.z + y40.w * gbv4.w;
                    float yg1 = y41.x * gbv4.x + y41.y * gbv4.y + y41.z * gbv4.z + y41.w * gbv4.w;
                    #pragma unroll
                    for (int m = 1; m <= 8; m <<= 1) {
                        n20 += __shfl_xor(n20, m, 64);
                        n21 += __shfl_xor(n21, m, 64);
                        yg0 += __shfl_xor(yg0, m, 64);
                        yg1 += __shfl_xor(yg1, m, 64);
                    }
                    n20 = n20 + 2.f * sc0 * yg0 + sc0 * sc0 * bb2o;
                    n21 = n21 + 2.f * sc1 * yg1 + sc1 * sc1 * bb2o;
                    float s0 = (n20 / (1.f + n20)) * rsqrtf(n20 + 1e-8f);
                    float s1 = (n21 / (1.f + n21)) * rsqrtf(n21 + 1e-8f);
                    vd0 = s0 * (yg0 + sc0 * bb2o);
                    vd1 = s1 * (yg1 + sc1 * bb2o);
                    if (GG == 0) {
                        float4 u0, u1;
                        u0.x = s0 * (a0.x + sc0 * gbv4.x); u0.y = s0 * (a0.y + sc0 * gbv4.y);
                        u0.z = s0 * (a0.z + sc0 * gbv4.z); u0.w = s0 * (a0.w + sc0 * gbv4.w);
                        u1.x = s1 * (a1.x + sc1 * gbv4.x); u1.y = s1 * (a1.y + sc1 * gbv4.y);
                        u1.z = s1 * (a1.z + sc1 * gbv4.z); u1.w = s1 * (a1.w + sc1 * gbv4.w);
                        *(float4*)&CC[row0 + 4 * Q] = u0;   // u rows
                        *(float4*)&CC[row1 + 4 * Q] = u1;
                    }
                }
                __builtin_amdgcn_wave_barrier();

                // ---- DB: db[i] = sum_c u[c] h[c][i] ----
                if (act) {
                    float4 d0 = make_float4(0.f, 0.f, 0.f, 0.f), d1 = d0;
                    #pragma unroll 8
                    for (int k = 0; k < 16; ++k) {
                        int c = 4 * k + GG;
                        float4 hc0 = *(const float4*)&HC[c * 68 + 4 * Q];
                        float ub0 = CC[row0 + c];
                        d0.x = fmaf(ub0, hc0.x, d0.x); d0.y = fmaf(ub0, hc0.y, d0.y);
                        d0.z = fmaf(ub0, hc0.z, d0.z); d0.w = fmaf(ub0, hc0.w, d0.w);
                        float4 hc1 = *(const float4*)&HC[4352 + c * 68 + 4 * Q];
                        float ub1 = CC[row1 + c];
                        d1.x = fmaf(ub1, hc1.x, d1.x); d1.y = fmaf(ub1, hc1.y, d1.y);
                        d1.z = fmaf(ub1, hc1.z, d1.z); d1.w = fmaf(ub1, hc1.w, d1.w);
                    }
                    #pragma unroll
                    for (int m = 16; m <= 32; m <<= 1) {
                        d0.x += __shfl_xor(d0.x, m, 64); d0.y += __shfl_xor(d0.y, m, 64);
                        d0.z += __shfl_xor(d0.z, m, 64); d0.w += __shfl_xor(d0.w, m, 64);
                        d1.x += __shfl_xor(d1.x, m, 64); d1.y += __shfl_xor(d1.y, m, 64);
                        d1.z += __shfl_xor(d1.z, m, 64); d1.w += __shfl_xor(d1.w, m, 64);
                    }
                    if (GG == 0) {
                        *(float4*)&CC[row0 + 4 * Q] = d0;
                        *(float4*)&CC[row1 + 4 * Q] = d1;
                    }
                }
                __builtin_amdgcn_wave_barrier();
                if (act) {
                    bl0 += CC[row0 + lane] + vd0;
                    bl1 += CC[row1 + lane] + vd1;
                }
            } else {
                // ---- iter 2: S via WT, squash, output v ----
                if (act) {
                    float4 s40 = make_float4(0.f, 0.f, 0.f, 0.f), s41 = s40;
                    #pragma unroll 8
                    for (int k = 0; k < 16; ++k) {
                        float4 w4 = *(const float4*)&pWT[k << 8];
                        float yb0 = CC[row0 + 4 * k + GG];
                        float yb1 = CC[row1 + 4 * k + GG];
                        s40.x = fmaf(w4.x, yb0, s40.x); s40.y = fmaf(w4.y, yb0, s40.y);
                        s40.z = fmaf(w4.z, yb0, s40.z); s40.w = fmaf(w4.w, yb0, s40.w);
                        s41.x = fmaf(w4.x, yb1, s41.x); s41.y = fmaf(w4.y, yb1, s41.y);
                        s41.z = fmaf(w4.z, yb1, s41.z); s41.w = fmaf(w4.w, yb1, s41.w);
                    }
                    #pragma unroll
                    for (int m = 16; m <= 32; m <<= 1) {
                        s40.x += __shfl_xor(s40.x, m, 64); s40.y += __shfl_xor(s40.y, m, 64);
                        s40.z += __shfl_xor(s40.z, m, 64); s40.w += __shfl_xor(s40.w, m, 64);
                        s41.x += __shfl_xor(s41.x, m, 64); s41.y += __shfl_xor(s41.y, m, 64);
                        s41.z += __shfl_xor(s41.z, m, 64); s41.w += __shfl_xor(s41.w, m, 64);
                    }
                    s40.x = fmaf(bias4.x, sc0, s40.x); s40.y = fmaf(bias4.y, sc0, s40.y);
                    s40.z = fmaf(bias4.z, sc0, s40.z); s40.w = fmaf(bias4.w, sc0, s40.w);
                    s41.x = fmaf(bias4.x, sc1, s41.x); s41.y = fmaf(bias4.y, sc1, s41.y);
                    s41.z = fmaf(bias4.z, sc1, s41.z); s41.w = fmaf(bias4.w, sc1, s41.w);
                    float n20 = s40.x * s40.x + s40.y * s40.y + s40.z * s40.z + s40.w * s40.w;
                    float n21 = s41.x * s41.x + s41.y * s41.y + s41.z * s41.z + s41.w * s41.w;
                    #pragma unroll
                    for (int m = 1; m <= 8; m <<= 1) {
                        n20 += __shfl_xor(n20, m, 64);
                        n21 += __shfl_xor(n21, m, 64);
                    }
                    float sl0 = (n20 / (1.f + n20)) * rsqrtf(n20 + 1e-8f);
                    float sl1 = (n21 / (1.f + n21)) * rsqrtf(n21 + 1e-8f);
                    float4 v0, v1;
                    v0.x = s40.x * sl0; v0.y = s40.y * sl0; v0.z = s40.z * sl0; v0.w = s40.w * sl0;
                    v1.x = s41.x * sl1; v1.y = s41.y * sl1; v1.z = s41.z * sl1; v1.w = s41.w * sl1;
                    if (FIN) {
                        if (q == 0 && GG == 0) {
                            *(float4*)&out[(size_t)(2 * p) * 640 + o * 64 + 4 * Q] = v0;
                            *(float4*)&out[(size_t)(2 * p + 1) * 640 + o * 64 + 4 * Q] = v1;
                        }
                    } else if (GG == 0) {
                        *(float4*)&CC[row0 + 4 * Q] = v0;   // v rows
                        *(float4*)&CC[row1 + 4 * Q] = v1;
                    }
                }
            }
        }

        // ---- layer epilogue (non-FIN): post v, rebuild OWN HC quarter ----
        if (!FIN) {
            __syncthreads();     // all v rows final in CC
            float* vb = vbuf + (size_t)B * 2048;
            if (t < 512)
                sys_st4(&vb[t * 4], *(const float4*)&CC[t * 4]);
            asm volatile("s_waitcnt vmcnt(0)" ::: "memory");
            __syncthreads();     // all waves' stores drained
            if (t == 0) SYS_ST(&flags[B * 16], step);
            // own 16 o's from CC while partners catch up
            #pragma unroll
            for (int rep = 0; rep < 2; ++rep) {
                int idx = rep * 1024 + t;
                int d = idx & 63, s = (idx >> 6) & 1, ol = idx >> 7;
                HC[s * 4352 + d * 68 + q * 16 + ol] = CC[idx];
            }
            __syncthreads();     // CC free for next layer's c rows
        }
    };

    layer(std::integral_constant<bool, false>{}, WT1, G1, gb1, bb21, b1,
          b_basic + (((size_t)0 * 128 + 2 * p) << 12),
          den0 + ((size_t)0 * 128 + 2 * p) * 64, false);
    layer(std::integral_constant<bool, false>{}, WT1, G1, gb1, bb21, b1,
          b_basic + (((size_t)1 * 128 + 2 * p) << 12),
          den0 + ((size_t)1 * 128 + 2 * p) * 64, true);
    layer(std::integral_constant<bool, false>{}, WT1, G1, gb1, bb21, b1,
          b_basic + (((size_t)2 * 128 + 2 * p) << 12),
          den0 + ((size_t)2 * 128 + 2 * p) * 64, true);
    layer(std::integral_constant<bool, true>{}, WT2, G2, gb2, bb22, b2,
          nullptr, nullptr, true);
}

extern "C" void kernel_launch(void* const* d_in, const int* in_sizes, int n_in,
                              void* d_out, int out_size, void* d_ws, size_t ws_size,
                              hipStream_t stream) {
    const float* x       = (const float*)d_in[0];
    const float* Wb      = (const float*)d_in[1];
    const float* bb      = (const float*)d_in[2];
    const float* W1      = (const float*)d_in[3];
    const float* b1      = (const float*)d_in[4];
    const float* W2      = (const float*)d_in[5];
    const float* b2      = (const float*)d_in[6];
    const float* b_basic = (const float*)d_in[7];
    const float* b_cls   = (const float*)d_in[8];
    float* out = (float*)d_out;

    float* h0    = (float*)d_ws;             // [128,64,64]   524288 f
    float* WT1   = h0   + 524288;            // [64,64,64]    262144
    float* WT2   = WT1  + 262144;            // [10,64,64]    40960
    float* G1    = WT2  + 40960;             // [64,64,64]    262144
    float* G2    = G1   + 262144;            // [10,64,64]    40960
    float* gb1   = G2   + 40960;             // [64,64]       4096
    float* gb2   = gb1  + 4096;              // [10,64]       640
    float* bb21  = gb2  + 640;               // [64]          64
    float* bb22  = bb21 + 64;                // [16]          16
    float* den0  = bb22 + 16;                // [3,128,64]    24576
    float* xbuf  = den0 + 24576;             // [2][256][128] 65536
    float* vbuf  = xbuf + 65536;             // [256][2048]   524288
    int*   flags = (int*)(vbuf + 524288);    // [4096]

    prep_kernel<<<379, 512, 0, stream>>>(x, Wb, bb, W1, b1, W2, b2, b_basic,
                                         h0, WT1, G1, gb1, bb21,
                                         WT2, G2, gb2, bb22, den0, flags);
    caps_fused<<<256, 1024, 0, stream>>>(h0, WT1, G1, gb1, bb21, b1,
                                         WT2, G2, gb2, bb22, b2,
                                         b_basic, b_cls, den0,
                                         xbuf, vbuf, flags, out);
}